// Round 2
// baseline (334.993 us; speedup 1.0000x reference)
//
#include <hip/hip_runtime.h>

typedef __attribute__((ext_vector_type(8))) short short8;
typedef __attribute__((ext_vector_type(4))) float floatx4;
typedef __attribute__((ext_vector_type(16))) float floatx16;
typedef unsigned short ushort_t;

#define S_LEN 4096
#define NH 12
#define DK 64
#define DM 768
#define BQ 128
#define LOG2E 1.4426950408889634f

static __device__ __forceinline__ unsigned short f2bf(float f) {
    unsigned int u = __float_as_uint(f);
    u += 0x7FFFu + ((u >> 16) & 1u);
    return (unsigned short)(u >> 16);
}
// async global->LDS, 16B per lane; LDS dest must be wave-uniform base + lane*16
static __device__ __forceinline__ void gld_lds16(const void* g, void* l) {
    __builtin_amdgcn_global_load_lds(
        (__attribute__((address_space(1))) void*)g,
        (__attribute__((address_space(3))) void*)l, 16, 0, 0);
}

// ---------------- weight transpose + bf16 cast: Wt[n][k] = W[k][n] ----------
__global__ __launch_bounds__(256)
void wtrans_kernel(const float* __restrict__ W0, const float* __restrict__ W1,
                   const float* __restrict__ W2, const float* __restrict__ W3,
                   ushort_t* __restrict__ T0, ushort_t* __restrict__ T1,
                   ushort_t* __restrict__ T2, ushort_t* __restrict__ T3) {
    __shared__ float tile[32][33];
    const int z = blockIdx.z;
    const float* W = (z == 0) ? W0 : (z == 1) ? W1 : (z == 2) ? W2 : W3;
    ushort_t* T = (z == 0) ? T0 : (z == 1) ? T1 : (z == 2) ? T2 : T3;
    const int bx = blockIdx.x, by = blockIdx.y;
    const int tx = threadIdx.x, ty = threadIdx.y;  // 32 x 8
    #pragma unroll
    for (int j = 0; j < 32; j += 8)
        tile[ty + j][tx] = W[(size_t)(by * 32 + ty + j) * DM + bx * 32 + tx];
    __syncthreads();
    #pragma unroll
    for (int j = 0; j < 32; j += 8)
        T[(size_t)(bx * 32 + ty + j) * DM + by * 32 + tx] = f2bf(tile[tx][ty + j]);
}

// ---------------- V transpose: Vn [bh][s][64] -> Vt [bh][64][s] -------------
__global__ __launch_bounds__(256)
void vtrans_kernel(const ushort_t* __restrict__ Vn, ushort_t* __restrict__ Vt) {
    __shared__ ushort_t tl[64 * 72];
    const int s0 = blockIdx.x * 64;
    const size_t bh = blockIdx.y;
    const int t = threadIdx.x;
    {
        const int r = t >> 2, c0 = (t & 3) * 16;
        const uint4* src = (const uint4*)(Vn + (bh * S_LEN + s0 + r) * DK + c0);
        uint4 a0 = src[0], a1 = src[1];
        uint4* dst = (uint4*)&tl[r * 72 + c0];
        dst[0] = a0;
        dst[1] = a1;
    }
    __syncthreads();
    {
        const int d = t >> 2, c0 = (t & 3) * 16;
        alignas(16) ushort_t tmp[16];
        #pragma unroll
        for (int j = 0; j < 16; ++j) tmp[j] = tl[(c0 + j) * 72 + d];
        uint4* dst = (uint4*)(Vt + (bh * DK + d) * S_LEN + s0 + c0);
        dst[0] = *(const uint4*)&tmp[0];
        dst[1] = *(const uint4*)&tmp[8];
    }
}

// ---------------- GEMM: C = A . Wt^T + bias ---------------------------------
// AF32=1: A is fp32, staged raw via global_load_lds, converted to bf16 in the
// fragment read (v_cvt_pk_bf16_f32) -- fuses the old cvt pass into the GEMM.
// Both A and B tiles use XOR chunk swizzle (inverse swizzle on the GLOBAL
// source address, linear LDS dest, swizzled read) for conflict-free ds_reads.
struct GemmArgs {
    const void* A[3];
    const ushort_t* Wt[3];
    const float* bias[3];
    void* C[3];
    float scale[3];
};

template <int MODE, int AF32>
__global__ __launch_bounds__(256, 3)
void gemm_kernel(GemmArgs args) {
    __shared__ __align__(16) ushort_t AsRaw[AF32 ? 128 * 32 * 2 : 128 * 32];
    __shared__ __align__(16) ushort_t Bs[128 * 32];
    const int z = blockIdx.z;
    const ushort_t* Wt = args.Wt[z];
    const float* bias = args.bias[z];
    void* Carg = args.C[z];
    const float scale = args.scale[z];

    const int m0 = blockIdx.x * 128;
    const int n0 = blockIdx.y * 128;
    const int t = threadIdx.x;
    const int w = t >> 6, lane = t & 63, l15 = lane & 15, quad = lane >> 4;
    const int rowoff = (w >> 1) * 64, coloff = (w & 1) * 64;

    floatx4 acc[4][4];
    #pragma unroll
    for (int i = 0; i < 4; ++i)
        #pragma unroll
        for (int j = 0; j < 4; ++j) acc[i][j] = (floatx4){0.f, 0.f, 0.f, 0.f};

    for (int kt = 0; kt < DM; kt += 32) {
        __syncthreads();
        if (AF32) {
            const float* Af = (const float*)args.A[z];
            // fp32 A tile 128x32 = 16KB, 16 insts; swizzle at 32B superchunks
            #pragma unroll
            for (int j = 0; j < 4; ++j) {
                const int r = (w * 4 + j) * 8 + (lane >> 3);
                const int c = lane & 7;  // 16B chunk 0..7
                const int sc = (((c >> 1) ^ (r & 3)) << 1) | (c & 1);
                gld_lds16(Af + (size_t)(m0 + r) * DM + kt + sc * 4,
                          (float*)AsRaw + r * 32 + c * 4);
            }
        } else {
            const ushort_t* Ab = (const ushort_t*)args.A[z];
            #pragma unroll
            for (int j = 0; j < 2; ++j) {
                const int r = j * 64 + w * 16 + (lane >> 2);
                const int c = lane & 3;  // 16B chunk 0..3
                const int sc = c ^ (r & 3);
                gld_lds16(Ab + (size_t)(m0 + r) * DM + kt + sc * 8,
                          &AsRaw[r * 32 + c * 8]);
            }
        }
        #pragma unroll
        for (int j = 0; j < 2; ++j) {
            const int r = j * 64 + w * 16 + (lane >> 2);
            const int c = lane & 3;
            const int sc = c ^ (r & 3);
            gld_lds16(Wt + (size_t)(n0 + r) * DM + kt + sc * 8,
                      &Bs[r * 32 + c * 8]);
        }
        __asm__ __volatile__("s_waitcnt vmcnt(0)" ::: "memory");
        __syncthreads();

        short8 af[4], bfr[4];
        if (AF32) {
            #pragma unroll
            for (int i = 0; i < 4; ++i) {
                const int r = rowoff + 16 * i + l15;
                const float* rp = (const float*)AsRaw + r * 32 + ((quad ^ (r & 3)) * 8);
                const float4 fa = *(const float4*)rp;
                const float4 fb = *(const float4*)(rp + 4);
                union { short8 s8; unsigned u[4]; } tt;
                asm("v_cvt_pk_bf16_f32 %0, %1, %2" : "=v"(tt.u[0]) : "v"(fa.x), "v"(fa.y));
                asm("v_cvt_pk_bf16_f32 %0, %1, %2" : "=v"(tt.u[1]) : "v"(fa.z), "v"(fa.w));
                asm("v_cvt_pk_bf16_f32 %0, %1, %2" : "=v"(tt.u[2]) : "v"(fb.x), "v"(fb.y));
                asm("v_cvt_pk_bf16_f32 %0, %1, %2" : "=v"(tt.u[3]) : "v"(fb.z), "v"(fb.w));
                af[i] = tt.s8;
            }
        } else {
            #pragma unroll
            for (int i = 0; i < 4; ++i) {
                const int r = rowoff + 16 * i + l15;
                af[i] = *(const short8*)&AsRaw[r * 32 + ((quad ^ (r & 3)) * 8)];
            }
        }
        #pragma unroll
        for (int j = 0; j < 4; ++j) {
            const int r = coloff + 16 * j + l15;
            bfr[j] = *(const short8*)&Bs[r * 32 + ((quad ^ (r & 3)) * 8)];
        }
        #pragma unroll
        for (int i = 0; i < 4; ++i)
            #pragma unroll
            for (int j = 0; j < 4; ++j)
                acc[i][j] = __builtin_amdgcn_mfma_f32_16x16x32_bf16(af[i], bfr[j], acc[i][j], 0, 0, 0);
    }

    #pragma unroll
    for (int i = 0; i < 4; ++i) {
        #pragma unroll
        for (int j = 0; j < 4; ++j) {
            #pragma unroll
            for (int reg = 0; reg < 4; ++reg) {
                const int m = m0 + rowoff + 16 * i + quad * 4 + reg;
                const int n = n0 + coloff + 16 * j + l15;
                const float v2 = (acc[i][j][reg] + bias[n]) * scale;
                if (MODE == 0) {
                    ushort_t* Out = (ushort_t*)Carg;
                    const int b = m >> 12, s = m & 4095, h = n >> 6, d = n & 63;
                    Out[((size_t)((b * NH + h) * S_LEN + s)) * DK + d] = f2bf(v2);
                } else {
                    float* Out = (float*)Carg;
                    Out[(size_t)m * DM + n] = v2;
                }
            }
        }
    }
}

// ---------------- flash attention: 32x32x16, async LDS staging --------------
// Q,K: bf16 [b][h][s][64] (Q pre-scaled 0.125*log2e); VT: bf16 [b][h][64][s].
// S^T[kv][q] = K(A) x Q(B regs).  Fixed-exponent softmax (exp2, no max).
// XOR-swizzled LDS; staging via global_load_lds with INVERSE swizzle applied
// to the global chunk address.  Double buffer, one barrier per KV iter.
// P stays IN REGISTERS (T12): v_cvt_pk_bf16_f32 + v_permlane32_swap_b32.
// Persistent zero vector feeds the first QK^T MFMA (no per-iter zero-init).
__global__ __launch_bounds__(256, 3)
void attn_kernel(const ushort_t* __restrict__ Q, const ushort_t* __restrict__ K,
                 const ushort_t* __restrict__ VT, const int* __restrict__ mask,
                 ushort_t* __restrict__ X) {
    __shared__ ushort_t Qs[BQ * DK];     // 16KB; Q staging only
    __shared__ ushort_t Ks0[64 * DK], Ks1[64 * DK];
    __shared__ ushort_t Vs0[64 * DK], Vs1[64 * DK];

    // XCD-locality swizzle: id&7 ~ XCD; each XCD owns 3 (b,h) pairs.
    const int id = blockIdx.x;
    const int per = id >> 3;
    const int bh = (id & 7) * 3 + (per >> 5);
    const int qb = per & 31;
    const int b = bh / NH, h = bh - b * NH;
    const size_t bho = (size_t)bh * S_LEN;
    const ushort_t* Vbase = VT + (size_t)bh * DK * S_LEN;
    const int t = threadIdx.x;
    const int w = t >> 6, lane = t & 63, l31 = lane & 31, half = lane >> 5;
    const int q0 = qb * BQ;
    const int swl = l31 & 7;
    const int frow8 = lane >> 3;  // fill: row within 8-row group
    const int fcc = lane & 7;     // fill: LDS chunk slot

    auto fillK = [&](int kv0, ushort_t* Kb) {
        #pragma unroll
        for (int j = 0; j < 2; ++j) {
            const int r = (w * 2 + j) * 8 + frow8;
            const int c8 = fcc ^ (r & 7);
            gld_lds16(K + (bho + kv0 + r) * DK + c8 * 8, &Kb[r * DK + fcc * 8]);
        }
    };
    auto fillV = [&](int kv0, ushort_t* Vb) {
        #pragma unroll
        for (int j = 0; j < 2; ++j) {
            const int r = (w * 2 + j) * 8 + frow8;
            const int c8 = fcc ^ (r & 7);
            gld_lds16(Vbase + (size_t)r * S_LEN + kv0 + c8 * 8, &Vb[r * DK + fcc * 8]);
        }
    };

    // prologue: async tile 0 + Q fill, mask all-ones reduction (barrier)
    fillK(0, Ks0);
    fillV(0, Vs0);
    #pragma unroll
    for (int j = 0; j < 4; ++j) {
        const int r = (w * 4 + j) * 8 + frow8;
        const int c8 = fcc ^ (r & 7);
        gld_lds16(Q + (bho + q0 + r) * DK + c8 * 8, &Qs[r * DK + fcc * 8]);
    }
    int ok = 1;
    {
        const int* mrow = mask + (size_t)b * S_LEN + t * 16;
        #pragma unroll
        for (int i = 0; i < 4; ++i) {
            const int4 mm = *(const int4*)(mrow + i * 4);
            ok &= (mm.x != 0) & (mm.y != 0) & (mm.z != 0) & (mm.w != 0);
        }
    }
    const int allones = __syncthreads_and(ok);  // barrier: fills drained

    short8 qf[4];  // Q fragments (B-operand), register-resident
    #pragma unroll
    for (int ks = 0; ks < 4; ++ks) {
        const int c8 = ks * 2 + half;
        qf[ks] = *(const short8*)&Qs[(w * 32 + l31) * DK + ((c8 ^ swl) << 3)];
    }

    floatx16 o[2];
    #pragma unroll
    for (int dt = 0; dt < 2; ++dt)
        #pragma unroll
        for (int r = 0; r < 16; ++r) o[dt][r] = 0.f;
    floatx16 zv;
    #pragma unroll
    for (int r = 0; r < 16; ++r) zv[r] = 0.f;
    float l_r = 0.f;

    auto body = [&](int it, const ushort_t* Kc, const ushort_t* Vc,
                    ushort_t* Kn, ushort_t* Vn) {
        __syncthreads();  // cur tile visible; all waves done reading nxt buffer
        if (it + 1 < S_LEN / 64) {
            fillK((it + 1) * 64, Kn);
            fillV((it + 1) * 64, Vn);
        }
        unsigned long long mb = ~0ULL;
        if (!allones) {
            const int mv = mask[(size_t)b * S_LEN + it * 64 + lane];
            mb = __ballot(mv != 0);
        }

        // S^T[kv][q]: 2 kv-tiles of 32; A=K rows (LDS), B=Q (regs)
        floatx16 st[2];
        __builtin_amdgcn_s_setprio(1);
        #pragma unroll
        for (int kt = 0; kt < 2; ++kt) {
            floatx16 s;
            {
                const int c8 = half;  // ks = 0, C = persistent zero vector
                const short8 kf = *(const short8*)&Kc[(kt * 32 + l31) * DK + ((c8 ^ swl) << 3)];
                s = __builtin_amdgcn_mfma_f32_32x32x16_bf16(kf, qf[0], zv, 0, 0, 0);
            }
            #pragma unroll
            for (int ks = 1; ks < 4; ++ks) {
                const int c8 = ks * 2 + half;
                const short8 kf = *(const short8*)&Kc[(kt * 32 + l31) * DK + ((c8 ^ swl) << 3)];
                s = __builtin_amdgcn_mfma_f32_32x32x16_bf16(kf, qf[ks], s, 0, 0, 0);
            }
            st[kt] = s;
        }
        __builtin_amdgcn_s_setprio(0);

        if (mb != ~0ULL) {
            #pragma unroll
            for (int kt = 0; kt < 2; ++kt) {
                const unsigned bits = (unsigned)(mb >> (kt * 32));
                const unsigned vbits = bits >> (half * 4);
                #pragma unroll
                for (int r = 0; r < 16; ++r)
                    if (!((vbits >> ((r & 3) + 8 * (r >> 2))) & 1)) st[kt][r] = -3.0e10f;
            }
        }

        // p = exp2(s); row-sum; P -> bf16 A-fragments fully in registers:
        // st: lane(l31)=q, kv = kt*32 + (r&3) + 8*(r>>2) + 4*half
        // pf[ks] needs  kv = ks*16 + 8*half + e  (e = reg order)
        short8 pf[4];
        #pragma unroll
        for (int kt = 0; kt < 2; ++kt) {
            float p[16];
            #pragma unroll
            for (int r = 0; r < 16; ++r) p[r] = __builtin_amdgcn_exp2f(st[kt][r]);
            #pragma unroll
            for (int g = 0; g < 4; ++g)
                l_r += (p[4 * g + 0] + p[4 * g + 1]) + (p[4 * g + 2] + p[4 * g + 3]);
            unsigned c0[4], c1[4];
            #pragma unroll
            for (int g = 0; g < 4; ++g) {
                asm("v_cvt_pk_bf16_f32 %0, %1, %2"
                    : "=v"(c0[g]) : "v"(p[4 * g + 0]), "v"(p[4 * g + 1]));
                asm("v_cvt_pk_bf16_f32 %0, %1, %2"
                    : "=v"(c1[g]) : "v"(p[4 * g + 2]), "v"(p[4 * g + 3]));
            }
            asm("v_permlane32_swap_b32 %0, %1" : "+v"(c0[0]), "+v"(c0[1]));
            asm("v_permlane32_swap_b32 %0, %1" : "+v"(c1[0]), "+v"(c1[1]));
            asm("v_permlane32_swap_b32 %0, %1" : "+v"(c0[2]), "+v"(c0[3]));
            asm("v_permlane32_swap_b32 %0, %1" : "+v"(c1[2]), "+v"(c1[3]));
            union { short8 s8; unsigned u[4]; } w0, w1;
            w0.u[0] = c0[0]; w0.u[1] = c1[0]; w0.u[2] = c0[1]; w0.u[3] = c1[1];
            w1.u[0] = c0[2]; w1.u[1] = c1[2]; w1.u[2] = c0[3]; w1.u[3] = c1[3];
            pf[kt * 2 + 0] = w0.s8;
            pf[kt * 2 + 1] = w1.s8;
        }

        // O[q][d] += P x V
        __builtin_amdgcn_s_setprio(1);
        #pragma unroll
        for (int dt = 0; dt < 2; ++dt) {
            #pragma unroll
            for (int ks = 0; ks < 4; ++ks) {
                const int c8 = ks * 2 + half;
                const short8 vf = *(const short8*)&Vc[(dt * 32 + l31) * DK + ((c8 ^ swl) << 3)];
                o[dt] = __builtin_amdgcn_mfma_f32_32x32x16_bf16(pf[ks], vf, o[dt], 0, 0, 0);
            }
        }
        __builtin_amdgcn_s_setprio(0);
    };

    for (int it = 0; it < S_LEN / 64; it += 2) {
        body(it, Ks0, Vs0, Ks1, Vs1);
        body(it + 1, Ks1, Vs1, Ks0, Vs0);
    }

    // full row sum for q = w*32 + l31 (halves cover disjoint kv)
    l_r += __shfl_xor(l_r, 32);
    const float inv = 1.0f / l_r;
    float iv[16];
    #pragma unroll
    for (int r = 0; r < 16; ++r)
        iv[r] = __shfl(inv, (r & 3) + 8 * (r >> 2) + 4 * half);
    #pragma unroll
    for (int dt = 0; dt < 2; ++dt)
        #pragma unroll
        for (int r = 0; r < 16; ++r) {
            const int qrow = (r & 3) + 8 * (r >> 2) + 4 * half;
            const int s = q0 + w * 32 + qrow;
            const int d = h * DK + dt * 32 + l31;
            X[((size_t)b * S_LEN + s) * DM + d] = f2bf(o[dt][r] * iv[r]);
        }
}

// ---------------- launch ----------------------------------------------------
extern "C" void kernel_launch(void* const* d_in, const int* in_sizes, int n_in,
                              void* d_out, int out_size, void* d_ws, size_t ws_size,
                              hipStream_t stream) {
    const float* q = (const float*)d_in[0];
    const float* k = (const float*)d_in[1];
    const float* v = (const float*)d_in[2];
    const int* mask = (const int*)d_in[3];
    const float* Wq = (const float*)d_in[4];
    const float* bq = (const float*)d_in[5];
    const float* Wk = (const float*)d_in[6];
    const float* bk = (const float*)d_in[7];
    const float* Wv = (const float*)d_in[8];
    const float* bv = (const float*)d_in[9];
    const float* Wo = (const float*)d_in[10];
    const float* bo = (const float*)d_in[11];
    float* out = (float*)d_out;

    const size_t ME = (size_t)2 * S_LEN * DM;
    const size_t WE = (size_t)DM * DM;
    ushort_t* Qb = (ushort_t*)d_ws;
    ushort_t* Kb = Qb + ME;
    ushort_t* Vb = Kb + ME;
    ushort_t* VTb = Vb + ME;
    ushort_t* Xb = VTb + ME;
    ushort_t* Wqt = Xb + ME;
    ushort_t* Wkt = Wqt + WE;
    ushort_t* Wvt = Wkt + WE;
    ushort_t* Wot = Wvt + WE;

    wtrans_kernel<<<dim3(DM / 32, DM / 32, 4), dim3(32, 8), 0, stream>>>(
        Wq, Wk, Wv, Wo, Wqt, Wkt, Wvt, Wot);

    GemmArgs g1;
    g1.A[0] = q;   g1.A[1] = k;   g1.A[2] = v;   // fp32 read directly (cvt fused)
    g1.Wt[0] = Wqt; g1.Wt[1] = Wkt; g1.Wt[2] = Wvt;
    g1.bias[0] = bq; g1.bias[1] = bk; g1.bias[2] = bv;
    g1.C[0] = Qb;  g1.C[1] = Kb;  g1.C[2] = Vb;
    g1.scale[0] = 0.125f * LOG2E;  // fold softmax scale + log2(e) into Q
    g1.scale[1] = 1.0f; g1.scale[2] = 1.0f;
    gemm_kernel<0, 1><<<dim3((2 * S_LEN) / 128, DM / 128, 3), 256, 0, stream>>>(g1);

    vtrans_kernel<<<dim3(S_LEN / 64, 2 * NH), 256, 0, stream>>>(Vb, VTb);

    attn_kernel<<<dim3(768), 256, 0, stream>>>(Qb, Kb, VTb, mask, Xb);

    GemmArgs g2;
    g2.A[0] = Xb;  g2.A[1] = Xb;  g2.A[2] = Xb;
    g2.Wt[0] = Wot; g2.Wt[1] = Wot; g2.Wt[2] = Wot;
    g2.bias[0] = bo; g2.bias[1] = bo; g2.bias[2] = bo;
    g2.C[0] = out; g2.C[1] = out; g2.C[2] = out;
    g2.scale[0] = 1.0f; g2.scale[1] = 1.0f; g2.scale[2] = 1.0f;
    gemm_kernel<1, 0><<<dim3((2 * S_LEN) / 128, DM / 128, 1), 256, 0, stream>>>(g2);
}

// Round 3
// 313.372 us; speedup vs baseline: 1.0690x; 1.0690x over previous
//
#include <hip/hip_runtime.h>

typedef __attribute__((ext_vector_type(8))) short short8;
typedef __attribute__((ext_vector_type(4))) float floatx4;
typedef __attribute__((ext_vector_type(16))) float floatx16;
typedef unsigned short ushort_t;

#define S_LEN 4096
#define NH 12
#define DK 64
#define DM 768
#define BQ 128
#define LOG2E 1.4426950408889634f

static __device__ __forceinline__ unsigned short f2bf(float f) {
    unsigned int u = __float_as_uint(f);
    u += 0x7FFFu + ((u >> 16) & 1u);
    return (unsigned short)(u >> 16);
}
static __device__ __forceinline__ unsigned pack2(float a, float b) {
    return (unsigned)f2bf(a) | ((unsigned)f2bf(b) << 16);
}
// async global->LDS, 16B per lane; LDS dest must be wave-uniform base + lane*16
static __device__ __forceinline__ void gld_lds16(const void* g, void* l) {
    __builtin_amdgcn_global_load_lds(
        (__attribute__((address_space(1))) void*)g,
        (__attribute__((address_space(3))) void*)l, 16, 0, 0);
}

// ---------------- weight transpose + bf16 cast: Wt[n][k] = W[k][n] ----------
__global__ __launch_bounds__(256)
void wtrans_kernel(const float* __restrict__ W0, const float* __restrict__ W1,
                   const float* __restrict__ W2, const float* __restrict__ W3,
                   ushort_t* __restrict__ T0, ushort_t* __restrict__ T1,
                   ushort_t* __restrict__ T2, ushort_t* __restrict__ T3) {
    __shared__ float tile[32][33];
    const int z = blockIdx.z;
    const float* W = (z == 0) ? W0 : (z == 1) ? W1 : (z == 2) ? W2 : W3;
    ushort_t* T = (z == 0) ? T0 : (z == 1) ? T1 : (z == 2) ? T2 : T3;
    const int bx = blockIdx.x, by = blockIdx.y;
    const int tx = threadIdx.x, ty = threadIdx.y;  // 32 x 8
    #pragma unroll
    for (int j = 0; j < 32; j += 8)
        tile[ty + j][tx] = W[(size_t)(by * 32 + ty + j) * DM + bx * 32 + tx];
    __syncthreads();
    #pragma unroll
    for (int j = 0; j < 32; j += 8)
        T[(size_t)(bx * 32 + ty + j) * DM + by * 32 + tx] = f2bf(tile[tx][ty + j]);
}

// ---------------- fp32 -> bf16 convert for q,k,v ----------------------------
__global__ __launch_bounds__(256)
void cvt_kernel(const float* __restrict__ A0, const float* __restrict__ A1,
                const float* __restrict__ A2, ushort_t* __restrict__ O0,
                ushort_t* __restrict__ O1, ushort_t* __restrict__ O2) {
    const int z = blockIdx.y;
    const float* A = (z == 0) ? A0 : (z == 1) ? A1 : A2;
    ushort_t* O = (z == 0) ? O0 : (z == 1) ? O1 : O2;
    const size_t i = ((size_t)blockIdx.x * 256 + threadIdx.x) * 8;
    const float4 f0 = *(const float4*)(A + i);
    const float4 f1 = *(const float4*)(A + i + 4);
    uint4 o;
    o.x = pack2(f0.x, f0.y);
    o.y = pack2(f0.z, f0.w);
    o.z = pack2(f1.x, f1.y);
    o.w = pack2(f1.z, f1.w);
    *(uint4*)(O + i) = o;
}

// ---------------- V transpose: Vn [bh][s][64] -> Vt [bh][64][s] -------------
__global__ __launch_bounds__(256)
void vtrans_kernel(const ushort_t* __restrict__ Vn, ushort_t* __restrict__ Vt) {
    __shared__ ushort_t tl[64 * 72];
    const int s0 = blockIdx.x * 64;
    const size_t bh = blockIdx.y;
    const int t = threadIdx.x;
    {
        const int r = t >> 2, c0 = (t & 3) * 16;
        const uint4* src = (const uint4*)(Vn + (bh * S_LEN + s0 + r) * DK + c0);
        uint4 a0 = src[0], a1 = src[1];
        uint4* dst = (uint4*)&tl[r * 72 + c0];
        dst[0] = a0;
        dst[1] = a1;
    }
    __syncthreads();
    {
        const int d = t >> 2, c0 = (t & 3) * 16;
        alignas(16) ushort_t tmp[16];
        #pragma unroll
        for (int j = 0; j < 16; ++j) tmp[j] = tl[(c0 + j) * 72 + d];
        uint4* dst = (uint4*)(Vt + (bh * DK + d) * S_LEN + s0 + c0);
        dst[0] = *(const uint4*)&tmp[0];
        dst[1] = *(const uint4*)&tmp[8];
    }
}

// ---------------- GEMM: C = A . Wt^T + bias ---------------------------------
// BK=64: 12 k-steps instead of 24 -> half the vmcnt(0)+barrier drains.
// LDS rows are 128B (full bank wrap), so reads use an XOR chunk swizzle:
// global source pre-permuted (chunk ^ (row&7)) within each 128B row,
// linear LDS dest (gld_lds lane-contiguous), XOR'd chunk on the read side.
struct GemmArgs {
    const ushort_t* A[3];
    const ushort_t* Wt[3];
    const float* bias[3];
    void* C[3];
    float scale[3];
};

template <int MODE>
__global__ __launch_bounds__(256, 3)
void gemm_kernel(GemmArgs args) {
    __shared__ __align__(16) ushort_t As[128 * 64];
    __shared__ __align__(16) ushort_t Bs[128 * 64];
    const int z = blockIdx.z;
    const ushort_t* A = args.A[z];
    const ushort_t* Wt = args.Wt[z];
    const float* bias = args.bias[z];
    void* Carg = args.C[z];
    const float scale = args.scale[z];

    const int m0 = blockIdx.x * 128;
    const int n0 = blockIdx.y * 128;
    const int t = threadIdx.x;
    const int w = t >> 6, lane = t & 63, l15 = lane & 15, quad = lane >> 4;
    const int rowoff = (w >> 1) * 64, coloff = (w & 1) * 64;
    const int srow = w * 8 + (lane >> 3);     // staging row within 32-row group
    const int schunk = lane & 7;              // LDS 16B chunk slot (linear)
    const int gchunk = schunk ^ (lane >> 3);  // inverse-swizzled global chunk

    floatx4 acc[4][4];
    #pragma unroll
    for (int i = 0; i < 4; ++i)
        #pragma unroll
        for (int j = 0; j < 4; ++j) acc[i][j] = (floatx4){0.f, 0.f, 0.f, 0.f};

    for (int kt = 0; kt < DM; kt += 64) {
        __syncthreads();
        #pragma unroll
        for (int j = 0; j < 4; ++j) {
            const int r = j * 32 + srow;
            gld_lds16(A + (size_t)(m0 + r) * DM + kt + gchunk * 8,
                      &As[r * 64 + schunk * 8]);
        }
        #pragma unroll
        for (int j = 0; j < 4; ++j) {
            const int r = j * 32 + srow;
            gld_lds16(Wt + (size_t)(n0 + r) * DM + kt + gchunk * 8,
                      &Bs[r * 64 + schunk * 8]);
        }
        __asm__ __volatile__("s_waitcnt vmcnt(0)" ::: "memory");
        __syncthreads();

        #pragma unroll
        for (int kk = 0; kk < 2; ++kk) {
            short8 af[4], bfr[4];
            #pragma unroll
            for (int i = 0; i < 4; ++i) {
                const int r = rowoff + 16 * i + l15;
                af[i] = *(const short8*)&As[r * 64 + (((kk * 4 + quad) ^ (r & 7)) << 3)];
            }
            #pragma unroll
            for (int j = 0; j < 4; ++j) {
                const int r = coloff + 16 * j + l15;
                bfr[j] = *(const short8*)&Bs[r * 64 + (((kk * 4 + quad) ^ (r & 7)) << 3)];
            }
            #pragma unroll
            for (int i = 0; i < 4; ++i)
                #pragma unroll
                for (int j = 0; j < 4; ++j)
                    acc[i][j] = __builtin_amdgcn_mfma_f32_16x16x32_bf16(af[i], bfr[j], acc[i][j], 0, 0, 0);
        }
    }

    #pragma unroll
    for (int i = 0; i < 4; ++i) {
        #pragma unroll
        for (int j = 0; j < 4; ++j) {
            #pragma unroll
            for (int reg = 0; reg < 4; ++reg) {
                const int m = m0 + rowoff + 16 * i + quad * 4 + reg;
                const int n = n0 + coloff + 16 * j + l15;
                const float v2 = (acc[i][j][reg] + bias[n]) * scale;
                if (MODE == 0) {
                    ushort_t* Out = (ushort_t*)Carg;
                    const int b = m >> 12, s = m & 4095, h = n >> 6, d = n & 63;
                    Out[((size_t)((b * NH + h) * S_LEN + s)) * DK + d] = f2bf(v2);
                } else {
                    float* Out = (float*)Carg;
                    Out[(size_t)m * DM + n] = v2;
                }
            }
        }
    }
}

// ---------------- flash attention: 32x32x16, async LDS staging --------------
// Q,K: bf16 [b][h][s][64] (Q pre-scaled 0.125*log2e); VT: bf16 [b][h][64][s].
// S^T[kv][q] = K(A) x Q(B regs).  Fixed-exponent softmax (exp2, no max).
// XOR-swizzled LDS; staging via global_load_lds with INVERSE swizzle applied
// to the global chunk address.  Double buffer, one barrier per KV iter.
// P stays IN REGISTERS (T12): v_cvt_pk_bf16_f32 + v_permlane32_swap_b32.
__global__ __launch_bounds__(256, 3)
void attn_kernel(const ushort_t* __restrict__ Q, const ushort_t* __restrict__ K,
                 const ushort_t* __restrict__ VT, const int* __restrict__ mask,
                 ushort_t* __restrict__ X) {
    __shared__ ushort_t Qs[BQ * DK];     // 16KB; Q staging only
    __shared__ ushort_t Ks0[64 * DK], Ks1[64 * DK];
    __shared__ ushort_t Vs0[64 * DK], Vs1[64 * DK];

    // XCD-locality swizzle: id&7 ~ XCD; each XCD owns 3 (b,h) pairs.
    const int id = blockIdx.x;
    const int per = id >> 3;
    const int bh = (id & 7) * 3 + (per >> 5);
    const int qb = per & 31;
    const int b = bh / NH, h = bh - b * NH;
    const size_t bho = (size_t)bh * S_LEN;
    const ushort_t* Vbase = VT + (size_t)bh * DK * S_LEN;
    const int t = threadIdx.x;
    const int w = t >> 6, lane = t & 63, l31 = lane & 31, half = lane >> 5;
    const int q0 = qb * BQ;
    const int swl = l31 & 7;
    const int frow8 = lane >> 3;  // fill: row within 8-row group
    const int fcc = lane & 7;     // fill: LDS chunk slot

    auto fillK = [&](int kv0, ushort_t* Kb) {
        #pragma unroll
        for (int j = 0; j < 2; ++j) {
            const int r = (w * 2 + j) * 8 + frow8;
            const int c8 = fcc ^ (r & 7);
            gld_lds16(K + (bho + kv0 + r) * DK + c8 * 8, &Kb[r * DK + fcc * 8]);
        }
    };
    auto fillV = [&](int kv0, ushort_t* Vb) {
        #pragma unroll
        for (int j = 0; j < 2; ++j) {
            const int r = (w * 2 + j) * 8 + frow8;
            const int c8 = fcc ^ (r & 7);
            gld_lds16(Vbase + (size_t)r * S_LEN + kv0 + c8 * 8, &Vb[r * DK + fcc * 8]);
        }
    };

    // prologue: async tile 0 + Q fill, mask all-ones reduction (barrier)
    fillK(0, Ks0);
    fillV(0, Vs0);
    #pragma unroll
    for (int j = 0; j < 4; ++j) {
        const int r = (w * 4 + j) * 8 + frow8;
        const int c8 = fcc ^ (r & 7);
        gld_lds16(Q + (bho + q0 + r) * DK + c8 * 8, &Qs[r * DK + fcc * 8]);
    }
    int ok = 1;
    {
        const int* mrow = mask + (size_t)b * S_LEN + t * 16;
        #pragma unroll
        for (int i = 0; i < 4; ++i) {
            const int4 mm = *(const int4*)(mrow + i * 4);
            ok &= (mm.x != 0) & (mm.y != 0) & (mm.z != 0) & (mm.w != 0);
        }
    }
    const int allones = __syncthreads_and(ok);  // barrier: fills drained

    short8 qf[4];  // Q fragments (B-operand), register-resident
    #pragma unroll
    for (int ks = 0; ks < 4; ++ks) {
        const int c8 = ks * 2 + half;
        qf[ks] = *(const short8*)&Qs[(w * 32 + l31) * DK + ((c8 ^ swl) << 3)];
    }

    floatx16 o[2];
    #pragma unroll
    for (int dt = 0; dt < 2; ++dt)
        #pragma unroll
        for (int r = 0; r < 16; ++r) o[dt][r] = 0.f;
    float l_r = 0.f;

    auto body = [&](int it, const ushort_t* Kc, const ushort_t* Vc,
                    ushort_t* Kn, ushort_t* Vn) {
        __syncthreads();  // cur tile visible; all waves done reading nxt buffer
        if (it + 1 < S_LEN / 64) {
            fillK((it + 1) * 64, Kn);
            fillV((it + 1) * 64, Vn);
        }
        unsigned long long mb = ~0ULL;
        if (!allones) {
            const int mv = mask[(size_t)b * S_LEN + it * 64 + lane];
            mb = __ballot(mv != 0);
        }

        // S^T[kv][q]: 2 kv-tiles of 32; A=K rows (LDS), B=Q (regs)
        floatx16 st[2];
        __builtin_amdgcn_s_setprio(1);
        #pragma unroll
        for (int kt = 0; kt < 2; ++kt) {
            floatx16 s;
            #pragma unroll
            for (int r = 0; r < 16; ++r) s[r] = 0.f;
            #pragma unroll
            for (int ks = 0; ks < 4; ++ks) {
                const int c8 = ks * 2 + half;
                const short8 kf = *(const short8*)&Kc[(kt * 32 + l31) * DK + ((c8 ^ swl) << 3)];
                s = __builtin_amdgcn_mfma_f32_32x32x16_bf16(kf, qf[ks], s, 0, 0, 0);
            }
            st[kt] = s;
        }
        __builtin_amdgcn_s_setprio(0);

        if (mb != ~0ULL) {
            #pragma unroll
            for (int kt = 0; kt < 2; ++kt) {
                const unsigned bits = (unsigned)(mb >> (kt * 32));
                const unsigned vbits = bits >> (half * 4);
                #pragma unroll
                for (int r = 0; r < 16; ++r)
                    if (!((vbits >> ((r & 3) + 8 * (r >> 2))) & 1)) st[kt][r] = -3.0e10f;
            }
        }

        // p = exp2(s); row-sum; P -> bf16 A-fragments fully in registers:
        // st: lane(l31)=q, kv = kt*32 + (r&3) + 8*(r>>2) + 4*half
        // pf[ks] needs  kv = ks*16 + 8*half + e  (e = reg order)
        short8 pf[4];
        #pragma unroll
        for (int kt = 0; kt < 2; ++kt) {
            float p[16];
            #pragma unroll
            for (int r = 0; r < 16; ++r) p[r] = __builtin_amdgcn_exp2f(st[kt][r]);
            #pragma unroll
            for (int g = 0; g < 4; ++g)
                l_r += (p[4 * g + 0] + p[4 * g + 1]) + (p[4 * g + 2] + p[4 * g + 3]);
            unsigned c0[4], c1[4];
            #pragma unroll
            for (int g = 0; g < 4; ++g) {
                asm("v_cvt_pk_bf16_f32 %0, %1, %2"
                    : "=v"(c0[g]) : "v"(p[4 * g + 0]), "v"(p[4 * g + 1]));
                asm("v_cvt_pk_bf16_f32 %0, %1, %2"
                    : "=v"(c1[g]) : "v"(p[4 * g + 2]), "v"(p[4 * g + 3]));
            }
            asm("v_permlane32_swap_b32 %0, %1" : "+v"(c0[0]), "+v"(c0[1]));
            asm("v_permlane32_swap_b32 %0, %1" : "+v"(c1[0]), "+v"(c1[1]));
            asm("v_permlane32_swap_b32 %0, %1" : "+v"(c0[2]), "+v"(c0[3]));
            asm("v_permlane32_swap_b32 %0, %1" : "+v"(c1[2]), "+v"(c1[3]));
            union { short8 s8; unsigned u[4]; } w0, w1;
            w0.u[0] = c0[0]; w0.u[1] = c1[0]; w0.u[2] = c0[1]; w0.u[3] = c1[1];
            w1.u[0] = c0[2]; w1.u[1] = c1[2]; w1.u[2] = c0[3]; w1.u[3] = c1[3];
            pf[kt * 2 + 0] = w0.s8;
            pf[kt * 2 + 1] = w1.s8;
        }

        // O[q][d] += P x V
        __builtin_amdgcn_s_setprio(1);
        #pragma unroll
        for (int dt = 0; dt < 2; ++dt) {
            #pragma unroll
            for (int ks = 0; ks < 4; ++ks) {
                const int c8 = ks * 2 + half;
                const short8 vf = *(const short8*)&Vc[(dt * 32 + l31) * DK + ((c8 ^ swl) << 3)];
                o[dt] = __builtin_amdgcn_mfma_f32_32x32x16_bf16(pf[ks], vf, o[dt], 0, 0, 0);
            }
        }
        __builtin_amdgcn_s_setprio(0);
    };

    for (int it = 0; it < S_LEN / 64; it += 2) {
        body(it, Ks0, Vs0, Ks1, Vs1);
        body(it + 1, Ks1, Vs1, Ks0, Vs0);
    }

    // full row sum for q = w*32 + l31 (halves cover disjoint kv)
    l_r += __shfl_xor(l_r, 32);
    const float inv = 1.0f / l_r;
    float iv[16];
    #pragma unroll
    for (int r = 0; r < 16; ++r)
        iv[r] = __shfl(inv, (r & 3) + 8 * (r >> 2) + 4 * half);
    #pragma unroll
    for (int dt = 0; dt < 2; ++dt)
        #pragma unroll
        for (int r = 0; r < 16; ++r) {
            const int qrow = (r & 3) + 8 * (r >> 2) + 4 * half;
            const int s = q0 + w * 32 + qrow;
            const int d = h * DK + dt * 32 + l31;
            X[((size_t)b * S_LEN + s) * DM + d] = f2bf(o[dt][r] * iv[r]);
        }
}

// ---------------- launch ----------------------------------------------------
extern "C" void kernel_launch(void* const* d_in, const int* in_sizes, int n_in,
                              void* d_out, int out_size, void* d_ws, size_t ws_size,
                              hipStream_t stream) {
    const float* q = (const float*)d_in[0];
    const float* k = (const float*)d_in[1];
    const float* v = (const float*)d_in[2];
    const int* mask = (const int*)d_in[3];
    const float* Wq = (const float*)d_in[4];
    const float* bq = (const float*)d_in[5];
    const float* Wk = (const float*)d_in[6];
    const float* bk = (const float*)d_in[7];
    const float* Wv = (const float*)d_in[8];
    const float* bv = (const float*)d_in[9];
    const float* Wo = (const float*)d_in[10];
    const float* bo = (const float*)d_in[11];
    float* out = (float*)d_out;

    const size_t ME = (size_t)2 * S_LEN * DM;
    const size_t WE = (size_t)DM * DM;
    ushort_t* Qb = (ushort_t*)d_ws;
    ushort_t* Kb = Qb + ME;
    ushort_t* Vb = Kb + ME;
    ushort_t* VTb = Vb + ME;
    ushort_t* Xb = VTb + ME;
    ushort_t* Wqt = Xb + ME;
    ushort_t* Wkt = Wqt + WE;
    ushort_t* Wvt = Wkt + WE;
    ushort_t* Wot = Wvt + WE;
    // bf16 copies of q,k,v aliased into regions dead until later stages:
    ushort_t* Qa = Xb;                 // Xb written only by attn
    ushort_t* Ka = VTb;                // VTb written only by vtrans
    ushort_t* Va = (ushort_t*)d_out;   // out written only by gemm2 (last)

    wtrans_kernel<<<dim3(DM / 32, DM / 32, 4), dim3(32, 8), 0, stream>>>(
        Wq, Wk, Wv, Wo, Wqt, Wkt, Wvt, Wot);

    cvt_kernel<<<dim3((int)(ME / 8 / 256), 3), 256, 0, stream>>>(q, k, v, Qa, Ka, Va);

    GemmArgs g1;
    g1.A[0] = Qa;  g1.A[1] = Ka;  g1.A[2] = Va;
    g1.Wt[0] = Wqt; g1.Wt[1] = Wkt; g1.Wt[2] = Wvt;
    g1.bias[0] = bq; g1.bias[1] = bk; g1.bias[2] = bv;
    g1.C[0] = Qb;  g1.C[1] = Kb;  g1.C[2] = Vb;
    g1.scale[0] = 0.125f * LOG2E;  // fold softmax scale + log2(e) into Q
    g1.scale[1] = 1.0f; g1.scale[2] = 1.0f;
    gemm_kernel<0><<<dim3((2 * S_LEN) / 128, DM / 128, 3), 256, 0, stream>>>(g1);

    vtrans_kernel<<<dim3(S_LEN / 64, 2 * NH), 256, 0, stream>>>(Vb, VTb);

    attn_kernel<<<dim3(768), 256, 0, stream>>>(Qb, Kb, VTb, mask, Xb);

    GemmArgs g2;
    g2.A[0] = Xb;  g2.A[1] = Xb;  g2.A[2] = Xb;
    g2.Wt[0] = Wot; g2.Wt[1] = Wot; g2.Wt[2] = Wot;
    g2.bias[0] = bo; g2.bias[1] = bo; g2.bias[2] = bo;
    g2.C[0] = out; g2.C[1] = out; g2.C[2] = out;
    g2.scale[0] = 1.0f; g2.scale[1] = 1.0f; g2.scale[2] = 1.0f;
    gemm_kernel<1><<<dim3((2 * S_LEN) / 128, DM / 128, 1), 256, 0, stream>>>(g2);
}